// Round 2
// baseline (388504.932 us; speedup 1.0000x reference)
//
#include <hip/hip_runtime.h>
#include <cstddef>

// Problem constants (fixed by reference)
#define BB   32
#define TT   2048
#define DIM  512
#define HH   1024
#define NBLK 256
#define NTHR 1024

typedef unsigned long long u64;

__device__ __forceinline__ float sigmoidf_(float x) {
    return 1.f / (1.f + __expf(-x));
}
__device__ __forceinline__ float tanhf_(float x) {
    float c = fminf(fmaxf(x, -15.f), 15.f);
    float e = __expf(2.f * c);
    return (e - 1.f) / (e + 1.f);
}

// Agent-scope (cross-XCD coherent, cache-bypassing) accesses for shared state.
__device__ __forceinline__ float cload(const float* p) {
    return __hip_atomic_load(p, __ATOMIC_RELAXED, __HIP_MEMORY_SCOPE_AGENT);
}
__device__ __forceinline__ void cstore(float* p, float v) {
    __hip_atomic_store(p, v, __ATOMIC_RELAXED, __HIP_MEMORY_SCOPE_AGENT);
}
__device__ __forceinline__ u64 cload64(const u64* p) {
    return __hip_atomic_load(p, __ATOMIC_RELAXED, __HIP_MEMORY_SCOPE_AGENT);
}
__device__ __forceinline__ void cstoreu(unsigned* p, unsigned v) {
    __hip_atomic_store(p, v, __ATOMIC_RELAXED, __HIP_MEMORY_SCOPE_AGENT);
}
__device__ __forceinline__ float dot4(float4 w, float a, float b, float c, float d) {
    return w.x * a + w.y * b + w.z * c + w.w * d;
}

// ---------------- setup kernels ----------------

__global__ void k_init(const float* __restrict__ x0, float* __restrict__ xT,
                       float* __restrict__ ha, float* __restrict__ hb,
                       unsigned* __restrict__ bar) {
    int i = blockIdx.x * blockDim.x + threadIdx.x;
    if (i < DIM * BB) { int d = i >> 5, b = i & 31; xT[d * BB + b] = x0[b * DIM + d]; }
    if (i < HH * BB) { ha[i] = 0.f; hb[i] = 0.f; }
    if (i < 8192) bar[i] = 0u;
}

// Wc[i][d] = sum_k W_ih[i][k] * W_enc[k][d]   (i<3072, d<512, k<1024)
__global__ void k_wc(const float* __restrict__ Wih, const float* __restrict__ Wenc,
                     float* __restrict__ Wc) {
    int db = blockIdx.x & 7, ib = blockIdx.x >> 3;
    int d = db * 64 + (threadIdx.x & 63);
    int i = ib * 4 + (threadIdx.x >> 6);
    const float4* wi4 = (const float4*)(Wih + (size_t)i * HH);
    float acc = 0.f;
    for (int k4 = 0; k4 < HH / 4; ++k4) {
        float4 w = wi4[k4];
        int k = k4 * 4;
        acc += w.x * Wenc[(size_t)(k + 0) * DIM + d];
        acc += w.y * Wenc[(size_t)(k + 1) * DIM + d];
        acc += w.z * Wenc[(size_t)(k + 2) * DIM + d];
        acc += w.w * Wenc[(size_t)(k + 3) * DIM + d];
    }
    Wc[(size_t)i * DIM + d] = acc;
}

// bc[i] = sum_k W_ih[i][k] * b_enc[k] + b_gru[i]
__global__ void k_bc(const float* __restrict__ Wih, const float* __restrict__ benc,
                     const float* __restrict__ bgru, float* __restrict__ bc) {
    int i = blockIdx.x;
    float s = 0.f;
    for (int k = threadIdx.x; k < HH; k += 256) s += Wih[(size_t)i * HH + k] * benc[k];
    __shared__ float red[256];
    red[threadIdx.x] = s; __syncthreads();
    for (int off = 128; off > 0; off >>= 1) {
        if (threadIdx.x < off) red[threadIdx.x] += red[threadIdx.x + off];
        __syncthreads();
    }
    if (threadIdx.x == 0) bc[i] = red[0] + bgru[i];
}

// ---------------- 1-hop grid barrier ----------------
// Packed per-block epoch flags (256 x u32 = 16 cachelines). Every block's
// wave0 polls ALL flags directly -> exit latency = one MALL round trip after
// the last arrival (no central release hop). All flag traffic relaxed
// agent-scope; data ordering via the vmcnt(0) drain __syncthreads performs
// before the arrival store (same reliance as the previous, passing version).
__device__ __forceinline__ void gbar(unsigned* flags, unsigned e) {
    __syncthreads();                       // all waves' coherent stores drained
    const int tid = threadIdx.x;
    if (tid == 0) cstoreu(&flags[blockIdx.x], e);
    if (tid < 64) {
        const u64* f8 = (const u64*)flags;
        const int i0 = tid * 2;            // lane covers flags[4*tid .. 4*tid+3]
        for (;;) {
            u64 a = cload64(f8 + i0);
            u64 c = cload64(f8 + i0 + 1);
            unsigned m0 = (unsigned)a, m1 = (unsigned)(a >> 32);
            unsigned m2 = (unsigned)c, m3 = (unsigned)(c >> 32);
            unsigned mn = m0 < m1 ? m0 : m1;
            unsigned mn2 = m2 < m3 ? m2 : m3;
            mn = mn < mn2 ? mn : mn2;
            if (__all(mn >= e)) break;
            __builtin_amdgcn_s_sleep(2);
        }
    }
    __syncthreads();
}

// ---------------- persistent recurrent kernel ----------------
// 1024 threads: tid = v*32 + b; v in [0,32) = K-chunk, b = batch lane.
// Per step t (entry: xT=x_t, h_t published, regs pr/pz/pn = U·h_t):
//   SEG_A: x-GEMM (Wc·x_t) added into pr/pz; LDS-reduce over v; finalize
//          h_{t+1}=GRU(h_t,x_t); publish. [short segment: only x-dependent work]
//   bar
//   SEG_H: ONE pass over h_{t+1} computing BOTH U·h_{t+1} (regs, for next
//          SEG_A) and Wdec·h_{t+1}; reduce; mu/sigma/x_{t+1}; publish xT.
//   bar
__global__ void __launch_bounds__(NTHR) k_gru(
    const float* __restrict__ Wc, const float* __restrict__ bc,
    const float* __restrict__ Whh, const float* __restrict__ Wdec,
    const float* __restrict__ bn, const float* __restrict__ bdec,
    const float* __restrict__ eps, float* __restrict__ xT,
    float* __restrict__ ha, float* __restrict__ hb,
    float* __restrict__ out, unsigned* __restrict__ bar)
{
    const int tid = threadIdx.x;
    const int b = tid & 31;
    const int v = tid >> 5;               // 0..31
    const int blk = blockIdx.x;

    __shared__ float sEx[4 * 32 * 4 * 32];   // 64 KB (exA; aliased as exD)
    __shared__ float sP[4 * 4 * 4 * 32];     // 8 KB  (pA; aliased as pD)
    #define EXA(c, vv, jj, bb) sEx[((((c) * 32 + (vv)) * 4 + (jj)) * 32) + (bb)]
    #define EXD(c, vv, bb)     sEx[(((c) * 32 + (vv)) * 32) + (bb)]
    #define PA(c, q, jj, bb)   sP[((((c) * 4 + (q)) * 4 + (jj)) * 32) + (bb)]
    #define PD(c, q, dd, bb)   sP[((((c) * 4 + (q)) * 2 + (dd)) * 32) + (bb)]

    // ---- A mapping: 4 GRU rows per block ----
    const int j0 = blk << 2;

    // finalize-A constants (tid<128: jj = tid>>5)
    float bcr = 0.f, bcz = 0.f, bcn = 0.f, bnj = 0.f;
    if (tid < 128) {
        int j = j0 + (tid >> 5);
        bcr = bc[j]; bcz = bc[j + HH]; bcn = bc[j + 2 * HH]; bnj = bn[j];
    }

    // ---- B mapping: XCD-swizzled column pair (blk%8 = XCD round-robin ->
    // each XCD owns 64 consecutive dcols = 4 full out/eps cachelines) ----
    const int p_ = ((blk & 7) << 5) + (blk >> 3);          // bijective
    const int dcol0 = p_ << 1;
    float bd0 = 0.f, bd1 = 0.f;
    if (tid < 64) {
        int dcol = dcol0 + (tid >> 5);
        bd0 = bdec[dcol]; bd1 = bdec[dcol + DIM];
    }

    const size_t TBD = (size_t)TT * BB * DIM;

    // U·h partials carried across iterations (h_0 = 0 -> start at 0)
    float pr[4] = {0, 0, 0, 0}, pz[4] = {0, 0, 0, 0}, pn[4] = {0, 0, 0, 0};

    for (int t = 0; t < TT; ++t) {
        const float* hprev = (t & 1) ? hb : ha;
        float* hnext = (t & 1) ? ha : hb;

        // ================= SEG_A: x-GEMM + gate finalize =================
        // prefetches (hidden under the x-GEMM)
        float ev = 0.f; size_t o = 0;
        if (tid < 64) {
            o = ((size_t)t * BB + b) * DIM + (dcol0 + (tid >> 5));
            ev = eps[o];                      // cached; used in SEG_H finalize
        }
        float hold = 0.f;
        if (tid < 128) hold = cload(&hprev[(size_t)(j0 + (tid >> 5)) * BB + b]);

        // issue all 16 x cloads up-front (deep MALL pipelining)
        float xv[16];
        #pragma unroll
        for (int i = 0; i < 16; ++i) xv[i] = cload(&xT[(v * 16 + i) * BB + b]);

        float xn_[4] = {0, 0, 0, 0};
        #pragma unroll
        for (int u = 0; u < 4; ++u) {
            const int k = v * 16 + u * 4;
            #pragma unroll
            for (int jj = 0; jj < 4; ++jj) {
                float4 wr = *(const float4*)(Wc + (size_t)(j0 + jj) * DIM + k);
                float4 wz = *(const float4*)(Wc + (size_t)(j0 + jj + HH) * DIM + k);
                float4 wn = *(const float4*)(Wc + (size_t)(j0 + jj + 2 * HH) * DIM + k);
                pr[jj] += dot4(wr, xv[u*4], xv[u*4+1], xv[u*4+2], xv[u*4+3]);
                pz[jj] += dot4(wz, xv[u*4], xv[u*4+1], xv[u*4+2], xv[u*4+3]);
                xn_[jj] += dot4(wn, xv[u*4], xv[u*4+1], xv[u*4+2], xv[u*4+3]);
            }
        }
        #pragma unroll
        for (int jj = 0; jj < 4; ++jj) {
            EXA(0, v, jj, b) = pr[jj];   // r: x + U combined
            EXA(1, v, jj, b) = pz[jj];   // z: x + U combined
            EXA(2, v, jj, b) = xn_[jj];  // n: x part
            EXA(3, v, jj, b) = pn[jj];   // n: U part (kept separate for r*(..))
        }
        __syncthreads();
        if (tid < 512) {                 // stage 1: 8-way partial over v
            const int rb = tid & 31, rjj = (tid >> 5) & 3, rq = tid >> 7;
            float s0 = 0, s1 = 0, s2 = 0, s3 = 0;
            #pragma unroll
            for (int i = 0; i < 8; ++i) {
                const int vv = rq * 8 + i;
                s0 += EXA(0, vv, rjj, rb); s1 += EXA(1, vv, rjj, rb);
                s2 += EXA(2, vv, rjj, rb); s3 += EXA(3, vv, rjj, rb);
            }
            PA(0, rq, rjj, rb) = s0; PA(1, rq, rjj, rb) = s1;
            PA(2, rq, rjj, rb) = s2; PA(3, rq, rjj, rb) = s3;
        }
        __syncthreads();
        if (tid < 128) {                 // stage 2 + gate math
            const int rjj = tid >> 5;
            float sr = 0, sz = 0, sx = 0, su = 0;
            #pragma unroll
            for (int q = 0; q < 4; ++q) {
                sr += PA(0, q, rjj, b); sz += PA(1, q, rjj, b);
                sx += PA(2, q, rjj, b); su += PA(3, q, rjj, b);
            }
            float r = sigmoidf_(sr + bcr);
            float z = sigmoidf_(sz + bcz);
            float n = tanhf_(sx + bcn + r * (su + bnj));
            cstore(&hnext[(size_t)(j0 + rjj) * BB + b], n + z * (hold - n));
        }
        gbar(bar, 2 * t + 1);

        // ================= SEG_H: merged U·h + decoder pass =================
        float hv[32];
        #pragma unroll
        for (int i = 0; i < 32; ++i) hv[i] = cload(&hnext[(v * 32 + i) * BB + b]);

        #pragma unroll
        for (int jj = 0; jj < 4; ++jj) { pr[jj] = 0.f; pz[jj] = 0.f; pn[jj] = 0.f; }
        float d0 = 0.f, d1 = 0.f, d2 = 0.f, d3 = 0.f;

        // pass 1: U rows r,z (8 weight streams)
        #pragma unroll
        for (int u = 0; u < 8; ++u) {
            const int k = v * 32 + u * 4;
            #pragma unroll
            for (int jj = 0; jj < 4; ++jj) {
                float4 ur = *(const float4*)(Whh + (size_t)(j0 + jj) * HH + k);
                float4 uz = *(const float4*)(Whh + (size_t)(j0 + jj + HH) * HH + k);
                pr[jj] += dot4(ur, hv[u*4], hv[u*4+1], hv[u*4+2], hv[u*4+3]);
                pz[jj] += dot4(uz, hv[u*4], hv[u*4+1], hv[u*4+2], hv[u*4+3]);
            }
        }
        // pass 2: U rows n + 4 decoder rows (8 weight streams)
        #pragma unroll
        for (int u = 0; u < 8; ++u) {
            const int k = v * 32 + u * 4;
            #pragma unroll
            for (int jj = 0; jj < 4; ++jj) {
                float4 un = *(const float4*)(Whh + (size_t)(j0 + jj + 2 * HH) * HH + k);
                pn[jj] += dot4(un, hv[u*4], hv[u*4+1], hv[u*4+2], hv[u*4+3]);
            }
            float4 w0 = *(const float4*)(Wdec + (size_t)(dcol0 + 0) * HH + k);
            float4 w1 = *(const float4*)(Wdec + (size_t)(dcol0 + 1) * HH + k);
            float4 w2 = *(const float4*)(Wdec + (size_t)(dcol0 + DIM) * HH + k);
            float4 w3 = *(const float4*)(Wdec + (size_t)(dcol0 + 1 + DIM) * HH + k);
            d0 += dot4(w0, hv[u*4], hv[u*4+1], hv[u*4+2], hv[u*4+3]);
            d1 += dot4(w1, hv[u*4], hv[u*4+1], hv[u*4+2], hv[u*4+3]);
            d2 += dot4(w2, hv[u*4], hv[u*4+1], hv[u*4+2], hv[u*4+3]);
            d3 += dot4(w3, hv[u*4], hv[u*4+1], hv[u*4+2], hv[u*4+3]);
        }
        EXD(0, v, b) = d0; EXD(1, v, b) = d1;   // mu(dcol0), mu(dcol0+1)
        EXD(2, v, b) = d2; EXD(3, v, b) = d3;   // ls(dcol0), ls(dcol0+1)
        __syncthreads();
        if (tid < 256) {                 // stage 1
            const int rb = tid & 31, rdd = (tid >> 5) & 1, rq = tid >> 6;
            float sm = 0, sl = 0;
            #pragma unroll
            for (int i = 0; i < 8; ++i) {
                const int vv = rq * 8 + i;
                sm += EXD(rdd, vv, rb);
                sl += EXD(2 + rdd, vv, rb);
            }
            PD(0, rq, rdd, rb) = sm; PD(1, rq, rdd, rb) = sl;
        }
        __syncthreads();
        if (tid < 64) {                  // stage 2 + sample
            const int dd = tid >> 5;
            float mu = bd0, ls = bd1;
            #pragma unroll
            for (int q = 0; q < 4; ++q) { mu += PD(0, q, dd, b); ls += PD(1, q, dd, b); }
            float sg = __expf(ls);
            float xn = mu + sg * ev;
            // cached stores: same-XCD blocks assemble full lines in local L2
            out[o] = xn;
            out[TBD + o] = mu;
            out[2 * TBD + o] = sg;
            cstore(&xT[(size_t)(dcol0 + dd) * BB + b], xn);
        }
        if (t + 1 < TT) gbar(bar, 2 * t + 2);
    }
    #undef EXA
    #undef EXD
    #undef PA
    #undef PD
}

// ---------------- launch ----------------

extern "C" void kernel_launch(void* const* d_in, const int* in_sizes, int n_in,
                              void* d_out, int out_size, void* d_ws, size_t ws_size,
                              hipStream_t stream) {
    const float* x0   = (const float*)d_in[0];
    const float* eps  = (const float*)d_in[1];
    const float* Wenc = (const float*)d_in[2];
    const float* benc = (const float*)d_in[3];
    const float* Wih  = (const float*)d_in[4];
    const float* Whh  = (const float*)d_in[5];
    const float* bgru = (const float*)d_in[6];
    const float* bn   = (const float*)d_in[7];
    const float* Wdec = (const float*)d_in[8];
    const float* bdec = (const float*)d_in[9];
    float* out = (float*)d_out;

    // workspace layout (floats): Wc | bc | xT | ha | hb | bar (8192 u32)
    float* ws = (float*)d_ws;
    float* Wc = ws;
    float* bc = Wc + (size_t)3 * HH * DIM;   // 1,572,864
    float* xT = bc + 3 * HH;                 // + 3072
    float* ha = xT + DIM * BB;               // + 16384
    float* hb = ha + HH * BB;                // + 32768
    unsigned* bar = (unsigned*)(hb + HH * BB);

    hipLaunchKernelGGL(k_init, dim3(128), dim3(256), 0, stream, x0, xT, ha, hb, bar);
    hipLaunchKernelGGL(k_wc, dim3(6144), dim3(256), 0, stream, Wih, Wenc, Wc);
    hipLaunchKernelGGL(k_bc, dim3(3072), dim3(256), 0, stream, Wih, benc, bgru, bc);

    void* args[] = { &Wc, &bc, (void*)&Whh, (void*)&Wdec, (void*)&bn, (void*)&bdec,
                     (void*)&eps, &xT, &ha, &hb, &out, &bar };
    hipLaunchCooperativeKernel((void*)k_gru, dim3(NBLK), dim3(NTHR), args, 0, stream);
}